// Round 6
// baseline (390.016 us; speedup 1.0000x reference)
//
#include <hip/hip_runtime.h>
#include <hip/hip_bf16.h>
#include <math.h>

#define Bq  2
#define Sq  512
#define Hq  768
#define NHq 12
#define HDq 64
#define SHsz (Bq * Sq * Hq)   // 786432 elems
#define WSZ  (Hq * Hq)        // 589824 elems
#define NBLK 512              // 2 blocks/CU -- large co-residency margin (LDS caps at 5/CU)

typedef __bf16 bf16x8 __attribute__((ext_vector_type(8)));
typedef unsigned short u16x8 __attribute__((ext_vector_type(8)));
typedef float f32x4 __attribute__((ext_vector_type(4)));

static __device__ __forceinline__ unsigned short f2bf(float f) {
    unsigned int u = __float_as_uint(f);
    u += 0x7fffu + ((u >> 16) & 1u);
    return (unsigned short)(u >> 16);
}
static __device__ __forceinline__ float bf2f(unsigned short v) {
    return __uint_as_float(((unsigned int)v) << 16);
}

static __device__ __forceinline__ f32x4 mfma_bf16(bf16x8 a, bf16x8 b, f32x4 c) {
    return __builtin_amdgcn_mfma_f32_16x16x32_bf16(a, b, c, 0, 0, 0);
}

static __device__ __forceinline__ void async16(const void* g, void* l) {
    __builtin_amdgcn_global_load_lds(
        (const __attribute__((address_space(1))) void*)(uintptr_t)g,
        (__attribute__((address_space(3))) void*)(unsigned int)(uintptr_t)l,
        16, 0, 0);
}

static __device__ __forceinline__ u16x8 cvt8(float4 a, float4 b) {
    u16x8 o = { f2bf(a.x), f2bf(a.y), f2bf(a.z), f2bf(a.w),
                f2bf(b.x), f2bf(b.y), f2bf(b.z), f2bf(b.w) };
    return o;
}

// Monotonic grid barrier in __device__ globals (not in the poisoned workspace).
// Monotone counting => correct across repeated launches / graph replays / rocprof
// replays with no reset. Timeout guard (~40ms @ 100MHz s_memrealtime) converts a
// would-be deadlock into a completed-but-wrong run => visible absmax diagnostic.
__device__ unsigned int g_bar[2] = {0u, 0u};

static __device__ __forceinline__ void grid_barrier(int which) {
    __threadfence();            // release (agent scope)
    __syncthreads();
    if (threadIdx.x == 0) {
        const unsigned int v =
            __hip_atomic_fetch_add(&g_bar[which], 1u, __ATOMIC_ACQ_REL,
                                   __HIP_MEMORY_SCOPE_AGENT) + 1u;
        const unsigned int target = ((v + (NBLK - 1u)) / NBLK) * NBLK;
        const long long t0 = (long long)__builtin_amdgcn_s_memrealtime();
        while (__hip_atomic_load(&g_bar[which], __ATOMIC_ACQUIRE,
                                 __HIP_MEMORY_SCOPE_AGENT) < target) {
            __builtin_amdgcn_s_sleep(2);
            if ((long long)__builtin_amdgcn_s_memrealtime() - t0 > 4000000LL) break;
        }
    }
    __syncthreads();
    __threadfence();            // acquire side for all threads
}

// One kernel, normal (graph-capturable) launch. Persistent blocks:
// phase1 cvt -> barrier -> phase2 proj (grid-stride over 768 tiles) -> barrier ->
// phase3 attn (grid-stride over 768 units).
__global__ __launch_bounds__(256, 2) void fused_kernel(
    const float* __restrict__ from_h, const float* __restrict__ to_h,
    const float* __restrict__ amask,
    const float* __restrict__ Wq,  const float* __restrict__ bq,
    const float* __restrict__ Wk,  const float* __restrict__ bk,
    const float* __restrict__ Wvf, const float* __restrict__ bvf,
    const float* __restrict__ Wvt, const float* __restrict__ bvt,
    float* __restrict__ outp, unsigned short* __restrict__ ws)
{
    __shared__ unsigned short lds[16384];   // 32 KB

    // workspace layout (same as verified 3-kernel version)
    unsigned short* qbf  = ws;
    unsigned short* kbf  = ws + SHsz;
    unsigned short* vtt  = ws + 2 * SHsz;
    unsigned short* fbf  = ws + 3 * SHsz;
    unsigned short* tbf  = ws + 4 * SHsz;
    unsigned short* wqb  = ws + 5 * SHsz;   // Wq,Wk,Wvf,Wvt contiguous
    unsigned short* vfb  = wqb + 4 * WSZ;

    const int bid = blockIdx.x;
    const int t   = threadIdx.x;

    // ---------------- phase 1: fp32 -> bf16 convert ----------------
    if (bid < 128) {
        const int g0 = bid * 256 + t;            // 0..32767, 3 chunks each (98304 total)
        #pragma unroll
        for (int it = 0; it < 3; ++it) {
            const int idx = (g0 + it * 32768) * 8;
            const float4 a = *(const float4*)(from_h + idx);
            const float4 b = *(const float4*)(from_h + idx + 4);
            *(u16x8*)(fbf + idx) = cvt8(a, b);
        }
    } else if (bid < 256) {
        const int g0 = (bid - 128) * 256 + t;
        #pragma unroll
        for (int it = 0; it < 3; ++it) {
            const int idx = (g0 + it * 32768) * 8;
            const float4 a = *(const float4*)(to_h + idx);
            const float4 b = *(const float4*)(to_h + idx + 4);
            *(u16x8*)(tbf + idx) = cvt8(a, b);
        }
    } else {
        // 4 weights contiguous: 294912 chunks over 65536 threads = 4 each + 32768 extra
        const int g0 = (bid - 256) * 256 + t;    // 0..65535
        #pragma unroll
        for (int it = 0; it < 4; ++it) {
            const int c  = g0 + it * 65536;      // 0..262143
            const int wi = c / 73728;            // WSZ/8
            const int off = c - wi * 73728;
            const float* src = (wi == 0) ? Wq : (wi == 1) ? Wk : (wi == 2) ? Wvf : Wvt;
            const float4 a = *(const float4*)(src + off * 8);
            const float4 b = *(const float4*)(src + off * 8 + 4);
            *(u16x8*)(wqb + c * 8) = cvt8(a, b);
        }
        if (g0 < 32768) {
            const int c  = g0 + 262144;          // 262144..294911 (all wi==3)
            const int off = c - 3 * 73728;
            const float4 a = *(const float4*)(Wvt + off * 8);
            const float4 b = *(const float4*)(Wvt + off * 8 + 4);
            *(u16x8*)(wqb + c * 8) = cvt8(a, b);
        }
    }

    grid_barrier(0);

    // ---------------- phase 2: projections C = A @ W^T + b (768 tiles) ----------------
    for (int wid = bid; wid < 768; wid += NBLK) {
        unsigned short* Als = lds;
        unsigned short* Wls = lds + 8192;

        const int z  = wid / 192;        // 0..3
        const int r  = wid - z * 192;
        const int bm = r / 12;           // 0..15
        const int bn = r - bm * 12;      // 0..11

        const unsigned short *A, *W;
        const float* bias;
        if (z == 0)      { A = fbf; W = wqb;           bias = bq;  }
        else if (z == 1) { A = tbf; W = wqb + WSZ;     bias = bk;  }
        else if (z == 2) { A = tbf; W = wqb + 3 * WSZ; bias = bvt; }
        else             { A = fbf; W = wqb + 2 * WSZ; bias = bvf; }

        const int wv   = t >> 6;
        const int lane = t & 63;
        const int l16  = lane & 15;
        const int quad = lane >> 4;
        const int srow = lane >> 3;                 // 0..7
        const int sgrp = (lane & 7) ^ (srow & 7);   // swizzled k-group

        f32x4 acc[4] = {};

        for (int kt = 0; kt < Hq / 128; ++kt) {
            __syncthreads();
            #pragma unroll
            for (int kh = 0; kh < 2; ++kh) {
                const int kc = kt * 128 + kh * 64;
                #pragma unroll
                for (int c = 0; c < 2; ++c) {
                    const int r0 = wv * 16 + c * 8;
                    async16(A + (size_t)(bm * 64 + r0 + srow) * Hq + kc + sgrp * 8, &Als[kh * 4096 + r0 * 64]);
                    async16(W + (size_t)(bn * 64 + r0 + srow) * Hq + kc + sgrp * 8, &Wls[kh * 4096 + r0 * 64]);
                }
            }
            __syncthreads();

            #pragma unroll
            for (int kh = 0; kh < 2; ++kh) {
                #pragma unroll
                for (int kk = 0; kk < 2; ++kk) {
                    const int sg = kh * 4096 + ((kk * 4 + quad) ^ (l16 & 7)) * 8;
                    const bf16x8 af = *(const bf16x8*)&Als[(wv * 16 + l16) * 64 + sg];
                    #pragma unroll
                    for (int j = 0; j < 4; ++j) {
                        const bf16x8 bfr = *(const bf16x8*)&Wls[(j * 16 + l16) * 64 + sg];
                        acc[j] = mfma_bf16(af, bfr, acc[j]);
                    }
                }
            }
        }

        __syncthreads();   // LDS free for repack

        unsigned short* rep = lds;   // stride 72 shorts
        if (z == 2) {
            #pragma unroll
            for (int j = 0; j < 4; ++j) {
                const float bv = bias[bn * 64 + j * 16 + l16];
                #pragma unroll
                for (int r2 = 0; r2 < 4; ++r2)
                    rep[(j * 16 + l16) * 72 + wv * 16 + quad * 4 + r2] = f2bf(acc[j][r2] + bv);
            }
        } else {
            #pragma unroll
            for (int j = 0; j < 4; ++j) {
                const float bv = bias[bn * 64 + j * 16 + l16];
                #pragma unroll
                for (int r2 = 0; r2 < 4; ++r2)
                    rep[(wv * 16 + quad * 4 + r2) * 72 + j * 16 + l16] = f2bf(acc[j][r2] + bv);
            }
        }
        __syncthreads();

        const int row = t >> 2;
        #pragma unroll
        for (int p = 0; p < 2; ++p) {
            const int col0 = ((t & 3) + p * 4) * 8;
            const u16x8 v = *(const u16x8*)&rep[row * 72 + col0];
            if (z == 2) {
                const int bb = bm >> 3, m0 = (bm & 7) * 64;
                *(u16x8*)&vtt[((size_t)((bb * NHq + bn) * HDq + row)) * Sq + m0 + col0] = v;
            } else {
                unsigned short* dstp = (z == 0) ? qbf : (z == 1) ? kbf : vfb;
                *(u16x8*)&dstp[(size_t)(bm * 64 + row) * Hq + bn * 64 + col0] = v;
            }
        }
        __syncthreads();   // protect rep before next iteration's staging
    }

    grid_barrier(1);

    // ---------------- phase 3: attention, split-K 4 waves (768 units) ----------------
    {
        unsigned short* Plds = lds;                         // 4*16*40 shorts = 5120 B
        float* Ols = (float*)(lds + 2560);                  // 3*16*68 floats = 13056 B
        float* Tls = (float*)(lds + 2560 + 6528);           // 48 floats

        const int wv   = t >> 6;       // 0..3
        const int lane = t & 63;
        const int l16  = lane & 15;
        const int quad = lane >> 4;
        const float scale = 0.125f;
        unsigned short* myP = &Plds[wv * 16 * 40];

        for (int wid = bid; wid < 768; wid += NBLK) {
            __syncthreads();           // LDS reuse across iterations

            const int b  = wid / 384;
            const int r3 = wid - b * 384;
            const int h  = r3 >> 5;        // 0..11
            const int q0 = (r3 & 31) * 16;

            const unsigned short* qrow = qbf + ((size_t)(b * Sq + q0 + l16)) * Hq + h * HDq + quad * 8;
            const bf16x8 aq0 = *(const bf16x8*)qrow;
            const bf16x8 aq1 = *(const bf16x8*)(qrow + 32);

            f32x4 O[4] = {};
            float ts[4] = {0.f, 0.f, 0.f, 0.f};

            for (int kt = 0; kt < 4; ++kt) {
                const int k0 = wv * 128 + kt * 32;
                const unsigned short* kr = kbf + ((size_t)(b * Sq + k0 + l16)) * Hq + h * HDq + quad * 8;
                const bf16x8 kb00 = *(const bf16x8*)kr;
                const bf16x8 kb01 = *(const bf16x8*)(kr + 32);
                const bf16x8 kb10 = *(const bf16x8*)(kr + 16 * Hq);
                const bf16x8 kb11 = *(const bf16x8*)(kr + 16 * Hq + 32);

                f32x4 s0 = {}, s1 = {};
                s0 = mfma_bf16(aq0, kb00, s0);
                s0 = mfma_bf16(aq1, kb01, s0);
                s1 = mfma_bf16(aq0, kb10, s1);
                s1 = mfma_bf16(aq1, kb11, s1);

                const float mk0 = amask[b * Sq + k0 + l16];
                const float mk1 = amask[b * Sq + k0 + 16 + l16];

                float p0[4], p1[4];
                #pragma unroll
                for (int r2 = 0; r2 < 4; ++r2) {
                    p0[r2] = __expf(s0[r2] * scale + mk0);
                    p1[r2] = __expf(s1[r2] * scale + mk1);
                    ts[r2] += p0[r2] + p1[r2];
                }

                #pragma unroll
                for (int r2 = 0; r2 < 4; ++r2) {
                    myP[(quad * 4 + r2) * 40 + l16]      = f2bf(p0[r2]);
                    myP[(quad * 4 + r2) * 40 + 16 + l16] = f2bf(p1[r2]);
                }
                const bf16x8 pa = *(const bf16x8*)&myP[l16 * 40 + quad * 8];

                const unsigned short* vr = vtt + ((size_t)((b * NHq + h) * HDq + l16)) * Sq + k0 + quad * 8;
                #pragma unroll
                for (int j = 0; j < 4; ++j) {
                    const bf16x8 vb = *(const bf16x8*)(vr + (size_t)j * 16 * Sq);
                    O[j] = mfma_bf16(pa, vb, O[j]);
                }
            }

            #pragma unroll
            for (int off = 1; off < 16; off <<= 1)
                #pragma unroll
                for (int r2 = 0; r2 < 4; ++r2) ts[r2] += __shfl_xor(ts[r2], off);

            if (wv > 0) {
                float* myO = &Ols[(wv - 1) * 16 * 68];
                #pragma unroll
                for (int j = 0; j < 4; ++j)
                    #pragma unroll
                    for (int r2 = 0; r2 < 4; ++r2)
                        myO[(quad * 4 + r2) * 68 + j * 16 + l16] = O[j][r2];
                if (l16 == 0)
                    #pragma unroll
                    for (int r2 = 0; r2 < 4; ++r2) Tls[(wv - 1) * 16 + quad * 4 + r2] = ts[r2];
            }
            __syncthreads();

            if (wv == 0) {
                #pragma unroll
                for (int r2 = 0; r2 < 4; ++r2) {
                    const int rr = quad * 4 + r2;
                    const float tot = ts[r2] + Tls[rr] + Tls[16 + rr] + Tls[32 + rr];
                    const float inv = 1.f / tot;
                    const int row = q0 + rr;
                    #pragma unroll
                    for (int j = 0; j < 4; ++j) {
                        const int col = h * HDq + j * 16 + l16;
                        const size_t idx = ((size_t)(b * Sq + row)) * Hq + col;
                        const float oj = O[j][r2]
                            + Ols[rr * 68 + j * 16 + l16]
                            + Ols[16 * 68 + rr * 68 + j * 16 + l16]
                            + Ols[2 * 16 * 68 + rr * 68 + j * 16 + l16];
                        outp[idx] = oj * inv + bf2f(vfb[idx]);
                    }
                }
            }
        }
    }
}

extern "C" void kernel_launch(void* const* d_in, const int* in_sizes, int n_in,
                              void* d_out, int out_size, void* d_ws, size_t ws_size,
                              hipStream_t stream) {
    (void)in_sizes; (void)n_in; (void)out_size; (void)ws_size;
    const float* from_h = (const float*)d_in[0];
    const float* to_h   = (const float*)d_in[1];
    const float* amask  = (const float*)d_in[2];
    const float* Wq  = (const float*)d_in[3];
    const float* bqv = (const float*)d_in[4];
    const float* Wk  = (const float*)d_in[5];
    const float* bkv = (const float*)d_in[6];
    const float* Wvf = (const float*)d_in[7];
    const float* bvf = (const float*)d_in[8];
    const float* Wvt = (const float*)d_in[9];
    const float* bvt = (const float*)d_in[10];
    float* outp = (float*)d_out;
    unsigned short* ws = (unsigned short*)d_ws;

    fused_kernel<<<dim3(NBLK), dim3(256), 0, stream>>>(
        from_h, to_h, amask, Wq, bqv, Wk, bkv, Wvf, bvf, Wvt, bvt, outp, ws);
}

// Round 7
// 105.542 us; speedup vs baseline: 3.6954x; 3.6954x over previous
//
#include <hip/hip_runtime.h>
#include <hip/hip_bf16.h>
#include <math.h>

#define Bq  2
#define Sq  512
#define Hq  768
#define NHq 12
#define HDq 64
#define SHsz (Bq * Sq * Hq)   // 786432 elems
#define WSZ  (Hq * Hq)        // 589824 elems

typedef __bf16 bf16x8 __attribute__((ext_vector_type(8)));
typedef unsigned short u16x8 __attribute__((ext_vector_type(8)));
typedef float f32x4 __attribute__((ext_vector_type(4)));

static __device__ __forceinline__ unsigned short f2bf(float f) {
    unsigned int u = __float_as_uint(f);
    u += 0x7fffu + ((u >> 16) & 1u);
    return (unsigned short)(u >> 16);
}
static __device__ __forceinline__ float bf2f(unsigned short v) {
    return __uint_as_float(((unsigned int)v) << 16);
}

static __device__ __forceinline__ f32x4 mfma_bf16(bf16x8 a, bf16x8 b, f32x4 c) {
    return __builtin_amdgcn_mfma_f32_16x16x32_bf16(a, b, c, 0, 0, 0);
}

static __device__ __forceinline__ void async16(const void* g, void* l) {
    __builtin_amdgcn_global_load_lds(
        (const __attribute__((address_space(1))) void*)(uintptr_t)g,
        (__attribute__((address_space(3))) void*)(unsigned int)(uintptr_t)l,
        16, 0, 0);
}

// ---------------- fp32 -> bf16 pre-convert (inputs + 4 weights) ----------------
__global__ __launch_bounds__(256) void cvt_kernel(
    const float* __restrict__ from_h, const float* __restrict__ to_h,
    const float* __restrict__ Wq, const float* __restrict__ Wk,
    const float* __restrict__ Wvf, const float* __restrict__ Wvt,
    unsigned short* __restrict__ ws)
{
    const int z = blockIdx.y;
    const float* src; unsigned short* dst; int n;
    switch (z) {
        case 0:  src = from_h; dst = ws + 3 * SHsz;           n = SHsz; break;
        case 1:  src = to_h;   dst = ws + 4 * SHsz;           n = SHsz; break;
        case 2:  src = Wq;     dst = ws + 5 * SHsz;           n = WSZ;  break;
        case 3:  src = Wk;     dst = ws + 5 * SHsz + WSZ;     n = WSZ;  break;
        case 4:  src = Wvf;    dst = ws + 5 * SHsz + 2 * WSZ; n = WSZ;  break;
        default: src = Wvt;    dst = ws + 5 * SHsz + 3 * WSZ; n = WSZ;  break;
    }
    const int idx = (blockIdx.x * 256 + threadIdx.x) * 8;
    if (idx < n) {
        const float4 a = *(const float4*)(src + idx);
        const float4 b = *(const float4*)(src + idx + 4);
        u16x8 o = { f2bf(a.x), f2bf(a.y), f2bf(a.z), f2bf(a.w),
                    f2bf(b.x), f2bf(b.y), f2bf(b.z), f2bf(b.w) };
        *(u16x8*)(dst + idx) = o;
    }
}

// ---------------- projections: C = A @ W^T + b, 64x64 tile, BK=128 (two 64-wide halves) ----------------
// z=0: Q -> qbf [B*S,H]; z=1: K -> kbf; z=2: VT -> vtt [(b*NH+h)*HD+d, S]; z=3: VF -> vfb bf16 [B*S,H]
__global__ __launch_bounds__(256) void proj_gemm(
    const unsigned short* __restrict__ fbf, const unsigned short* __restrict__ tbf,
    const unsigned short* __restrict__ wqb, const unsigned short* __restrict__ wkb,
    const unsigned short* __restrict__ wvfb, const unsigned short* __restrict__ wvtb,
    const float* __restrict__ bq, const float* __restrict__ bk,
    const float* __restrict__ bvf, const float* __restrict__ bvt,
    unsigned short* __restrict__ qbf, unsigned short* __restrict__ kbf,
    unsigned short* __restrict__ vtt, unsigned short* __restrict__ vfb)
{
    __shared__ unsigned short lds[16384];  // A halves [0,8192), W halves [8192,16384)
    unsigned short* Als = lds;
    unsigned short* Wls = lds + 8192;

    const int z = blockIdx.z;
    const unsigned short *A, *W;
    const float* bias;
    if (z == 0)      { A = fbf; W = wqb;  bias = bq;  }
    else if (z == 1) { A = tbf; W = wkb;  bias = bk;  }
    else if (z == 2) { A = tbf; W = wvtb; bias = bvt; }
    else             { A = fbf; W = wvfb; bias = bvf; }

    const int t    = threadIdx.x;
    const int wv   = t >> 6;
    const int lane = t & 63;
    const int l16  = lane & 15;
    const int quad = lane >> 4;
    const int bn = blockIdx.x;   // 0..11
    const int bm = blockIdx.y;   // 0..15

    const int srow = lane >> 3;                 // 0..7
    const int sgrp = (lane & 7) ^ (srow & 7);   // logical k-group for the swizzled store slot

    f32x4 acc[4] = {};

    for (int kt = 0; kt < Hq / 128; ++kt) {
        __syncthreads();
        #pragma unroll
        for (int kh = 0; kh < 2; ++kh) {
            const int kc = kt * 128 + kh * 64;
            #pragma unroll
            for (int c = 0; c < 2; ++c) {
                const int r0 = wv * 16 + c * 8;
                async16(A + (size_t)(bm * 64 + r0 + srow) * Hq + kc + sgrp * 8, &Als[kh * 4096 + r0 * 64]);
                async16(W + (size_t)(bn * 64 + r0 + srow) * Hq + kc + sgrp * 8, &Wls[kh * 4096 + r0 * 64]);
            }
        }
        __syncthreads();

        #pragma unroll
        for (int kh = 0; kh < 2; ++kh) {
            #pragma unroll
            for (int kk = 0; kk < 2; ++kk) {
                const int sg = kh * 4096 + ((kk * 4 + quad) ^ (l16 & 7)) * 8;
                const bf16x8 af = *(const bf16x8*)&Als[(wv * 16 + l16) * 64 + sg];
                #pragma unroll
                for (int j = 0; j < 4; ++j) {
                    const bf16x8 bfr = *(const bf16x8*)&Wls[(j * 16 + l16) * 64 + sg];
                    acc[j] = mfma_bf16(af, bfr, acc[j]);
                }
            }
        }
    }

    __syncthreads();   // LDS free for repack

    unsigned short* rep = lds;   // stride 72 shorts (144 B, 16B-aligned)
    if (z == 2) {
        // transposed repack: rep[n_local][m_local]
        #pragma unroll
        for (int j = 0; j < 4; ++j) {
            const float bv = bias[bn * 64 + j * 16 + l16];
            #pragma unroll
            for (int r = 0; r < 4; ++r)
                rep[(j * 16 + l16) * 72 + wv * 16 + quad * 4 + r] = f2bf(acc[j][r] + bv);
        }
    } else {
        #pragma unroll
        for (int j = 0; j < 4; ++j) {
            const float bv = bias[bn * 64 + j * 16 + l16];
            #pragma unroll
            for (int r = 0; r < 4; ++r)
                rep[(wv * 16 + quad * 4 + r) * 72 + j * 16 + l16] = f2bf(acc[j][r] + bv);
        }
    }
    __syncthreads();

    const int row = t >> 2;
    #pragma unroll
    for (int p = 0; p < 2; ++p) {
        const int col0 = ((t & 3) + p * 4) * 8;
        const u16x8 v = *(const u16x8*)&rep[row * 72 + col0];
        if (z == 2) {
            const int bb = bm >> 3, m0 = (bm & 7) * 64;
            *(u16x8*)&vtt[((size_t)((bb * NHq + bn) * HDq + row)) * Sq + m0 + col0] = v;
        } else {
            unsigned short* dstp = (z == 0) ? qbf : (z == 1) ? kbf : vfb;
            *(u16x8*)&dstp[(size_t)(bm * 64 + row) * Hq + bn * 64 + col0] = v;
        }
    }
}

// ---------------- attention, split-K: 2 waves/block each cover 256 k-positions ----------------
// out = softmax(QK^T/8 + mask) @ VT + VF. Partials additive (no running max), combined via LDS.
__global__ __launch_bounds__(128) void attn_kernel(
    const unsigned short* __restrict__ qbf,
    const unsigned short* __restrict__ kbf,
    const unsigned short* __restrict__ vtt,
    const unsigned short* __restrict__ vfb,
    const float* __restrict__ amask,
    float* __restrict__ outp)
{
    __shared__ unsigned short Plds[2 * 16 * 40];   // per-wave P repack
    __shared__ float Ols[16 * 68];                 // wave1 partial O (2-way max)
    __shared__ float Tls[16];                      // wave1 partial denom

    const int t    = threadIdx.x;
    const int wv   = t >> 6;       // k-range split
    const int lane = t & 63;
    const int l16  = lane & 15;
    const int quad = lane >> 4;
    const int q0 = blockIdx.x * 16;
    const int h  = blockIdx.y;
    const int b  = blockIdx.z;

    const unsigned short* qrow = qbf + ((size_t)(b * Sq + q0 + l16)) * Hq + h * HDq + quad * 8;
    const bf16x8 aq0 = *(const bf16x8*)qrow;
    const bf16x8 aq1 = *(const bf16x8*)(qrow + 32);

    f32x4 O[4] = {};
    float ts[4] = {0.f, 0.f, 0.f, 0.f};
    const float scale = 0.125f;
    unsigned short* myP = &Plds[wv * 16 * 40];

    for (int kt = 0; kt < 8; ++kt) {
        const int k0 = wv * 256 + kt * 32;
        const unsigned short* kr = kbf + ((size_t)(b * Sq + k0 + l16)) * Hq + h * HDq + quad * 8;
        const bf16x8 kb00 = *(const bf16x8*)kr;
        const bf16x8 kb01 = *(const bf16x8*)(kr + 32);
        const bf16x8 kb10 = *(const bf16x8*)(kr + 16 * Hq);
        const bf16x8 kb11 = *(const bf16x8*)(kr + 16 * Hq + 32);

        f32x4 s0 = {}, s1 = {};
        s0 = mfma_bf16(aq0, kb00, s0);
        s0 = mfma_bf16(aq1, kb01, s0);
        s1 = mfma_bf16(aq0, kb10, s1);
        s1 = mfma_bf16(aq1, kb11, s1);

        const float mk0 = amask[b * Sq + k0 + l16];
        const float mk1 = amask[b * Sq + k0 + 16 + l16];

        float p0[4], p1[4];
        #pragma unroll
        for (int r = 0; r < 4; ++r) {
            p0[r] = __expf(s0[r] * scale + mk0);
            p1[r] = __expf(s1[r] * scale + mk1);
            ts[r] += p0[r] + p1[r];
        }

        #pragma unroll
        for (int r = 0; r < 4; ++r) {
            myP[(quad * 4 + r) * 40 + l16]      = f2bf(p0[r]);
            myP[(quad * 4 + r) * 40 + 16 + l16] = f2bf(p1[r]);
        }
        const bf16x8 pa = *(const bf16x8*)&myP[l16 * 40 + quad * 8];

        const unsigned short* vr = vtt + ((size_t)((b * NHq + h) * HDq + l16)) * Sq + k0 + quad * 8;
        #pragma unroll
        for (int j = 0; j < 4; ++j) {
            const bf16x8 vb = *(const bf16x8*)(vr + (size_t)j * 16 * Sq);
            O[j] = mfma_bf16(pa, vb, O[j]);
        }
    }

    #pragma unroll
    for (int off = 1; off < 16; off <<= 1)
        #pragma unroll
        for (int r = 0; r < 4; ++r) ts[r] += __shfl_xor(ts[r], off);

    if (wv == 1) {
        #pragma unroll
        for (int j = 0; j < 4; ++j)
            #pragma unroll
            for (int r = 0; r < 4; ++r)
                Ols[(quad * 4 + r) * 68 + j * 16 + l16] = O[j][r];
        if (l16 == 0)
            #pragma unroll
            for (int r = 0; r < 4; ++r) Tls[quad * 4 + r] = ts[r];
    }
    __syncthreads();
    if (wv == 1) return;

    #pragma unroll
    for (int r = 0; r < 4; ++r) {
        const float inv = 1.f / (ts[r] + Tls[quad * 4 + r]);
        const int row = q0 + quad * 4 + r;
        #pragma unroll
        for (int j = 0; j < 4; ++j) {
            const int col = h * HDq + j * 16 + l16;
            const size_t idx = ((size_t)(b * Sq + row)) * Hq + col;
            const float oj = O[j][r] + Ols[(quad * 4 + r) * 68 + j * 16 + l16];
            outp[idx] = oj * inv + bf2f(vfb[idx]);
        }
    }
}

extern "C" void kernel_launch(void* const* d_in, const int* in_sizes, int n_in,
                              void* d_out, int out_size, void* d_ws, size_t ws_size,
                              hipStream_t stream) {
    (void)in_sizes; (void)n_in; (void)out_size; (void)ws_size;
    const float* from_h = (const float*)d_in[0];
    const float* to_h   = (const float*)d_in[1];
    const float* amask  = (const float*)d_in[2];
    const float* Wq  = (const float*)d_in[3];
    const float* bqv = (const float*)d_in[4];
    const float* Wk  = (const float*)d_in[5];
    const float* bkv = (const float*)d_in[6];
    const float* Wvf = (const float*)d_in[7];
    const float* bvf = (const float*)d_in[8];
    const float* Wvt = (const float*)d_in[9];
    const float* bvt = (const float*)d_in[10];
    float* outp = (float*)d_out;

    unsigned short* ws = (unsigned short*)d_ws;
    unsigned short* qbf = ws;
    unsigned short* kbf = ws + SHsz;
    unsigned short* vtt = ws + 2 * SHsz;
    unsigned short* fbf = ws + 3 * SHsz;
    unsigned short* tbf = ws + 4 * SHsz;
    unsigned short* wqb  = ws + 5 * SHsz;
    unsigned short* wkb  = wqb + WSZ;
    unsigned short* wvfb = wqb + 2 * WSZ;
    unsigned short* wvtb = wqb + 3 * WSZ;
    unsigned short* vfb  = wqb + 4 * WSZ;

    cvt_kernel<<<dim3(384, 6), 256, 0, stream>>>(from_h, to_h, Wq, Wk, Wvf, Wvt, ws);

    dim3 gp(12, 16, 4);
    proj_gemm<<<gp, 256, 0, stream>>>(fbf, tbf, wqb, wkb, wvfb, wvtb,
                                      bqv, bkv, bvf, bvt, qbf, kbf, vtt, vfb);

    dim3 ga(Sq / 16, NHq, Bq);
    attn_kernel<<<ga, 128, 0, stream>>>(qbf, kbf, vtt, vfb, amask, outp);
}